// Round 3
// baseline (5821.312 us; speedup 1.0000x reference)
//
#include <hip/hip_runtime.h>
#include <hip/hip_bf16.h>

#define NB 256
#define TT 128
#define DD 1024
#define HH 1024
#define FH 4096
#define KTOT 3072

typedef __attribute__((ext_vector_type(4))) float f32x4;
typedef __attribute__((ext_vector_type(8))) short short8;

__device__ __forceinline__ unsigned short f2bf(float f) {
    union { float f; unsigned u; } v; v.f = f;
    unsigned u = v.u;
    u += 0x7FFFu + ((u >> 16) & 1u);   // RNE
    return (unsigned short)(u >> 16);
}
__device__ __forceinline__ float sigm(float v) { return 1.f / (1.f + __expf(-v)); }
__device__ __forceinline__ float tanhf_(float v) { return 1.f - 2.f / (__expf(2.f * v) + 1.f); }

// block id -> (row tile m0, j tile j0); j-tile aligned to XCD (bid&7) for L2 locality
__device__ __forceinline__ void bmap(int bid, int& m0, int& j0) {
    int x = bid & 7, y = (bid >> 3) & 7, mt = bid >> 6;
    m0 = mt * 64;
    j0 = (x * 8 + y) * 16;
}

__device__ __forceinline__ short8 pack8(float4 v0, float4 v1) {
    short8 r;
    r[0] = (short)f2bf(v0.x); r[1] = (short)f2bf(v0.y);
    r[2] = (short)f2bf(v0.z); r[3] = (short)f2bf(v0.w);
    r[4] = (short)f2bf(v1.x); r[5] = (short)f2bf(v1.y);
    r[6] = (short)f2bf(v1.z); r[7] = (short)f2bf(v1.w);
    return r;
}

// ---------------------------------------------------------------------------
// Wt[c][k] bf16, c = pre column (gate*1024 + j), k = concat(x,h,attn) index
// ---------------------------------------------------------------------------
__global__ __launch_bounds__(256) void wt_prep(const float* __restrict__ Wx,
                                               const float* __restrict__ Wh,
                                               const float* __restrict__ Wattn,
                                               unsigned short* __restrict__ Wt) {
    __shared__ unsigned short tile[64][65];
    int k0 = blockIdx.x * 64;   // 48
    int c0 = blockIdx.y * 64;   // 64
    const float* src; int kl0;
    if (k0 < 1024)      { src = Wx;    kl0 = k0; }
    else if (k0 < 2048) { src = Wh;    kl0 = k0 - 1024; }
    else                { src = Wattn; kl0 = k0 - 2048; }
    int tid = threadIdx.x;
    int r = tid >> 2;
    int ch = (tid & 3) << 4;
    const float* p = src + (size_t)(kl0 + r) * FH + c0 + ch;
#pragma unroll
    for (int i = 0; i < 16; i += 4) {
        float4 v = *reinterpret_cast<const float4*>(p + i);
        tile[r][ch + i + 0] = f2bf(v.x);
        tile[r][ch + i + 1] = f2bf(v.y);
        tile[r][ch + i + 2] = f2bf(v.z);
        tile[r][ch + i + 3] = f2bf(v.w);
    }
    __syncthreads();
    alignas(16) unsigned short vals[16];
#pragma unroll
    for (int i = 0; i < 16; ++i) vals[i] = tile[ch + i][r];
    unsigned short* q = Wt + (size_t)(c0 + r) * KTOT + k0 + ch;
    *reinterpret_cast<uint4*>(q)     = *reinterpret_cast<uint4*>(&vals[0]);
    *reinterpret_cast<uint4*>(q + 8) = *reinterpret_cast<uint4*>(&vals[8]);
}

__global__ __launch_bounds__(256) void zero_buf(float* __restrict__ p, int n) {
    int i = blockIdx.x * 256 + threadIdx.x;
    if (i < n) p[i] = 0.f;
}

// ---------------------------------------------------------------------------
// init: h0 = c0 = mean(Af[n,h,:]); write hcat h-slot0 (bf16) + c; logits(h0) -> lg0
// ---------------------------------------------------------------------------
__global__ __launch_bounds__(512) void init_kernel(const float* __restrict__ A,
                                                   float* __restrict__ c,
                                                   unsigned short* __restrict__ hcat,
                                                   float* __restrict__ lg0) {
    int m0, j0; bmap(blockIdx.x, m0, j0);
    int tid = threadIdx.x;
    int r = tid >> 3, j2 = (tid & 7) * 2;
    int n = m0 + r;
    float lg[16];
#pragma unroll
    for (int l = 0; l < 16; ++l) lg[l] = 0.f;
#pragma unroll
    for (int e = 0; e < 2; ++e) {
        int j = j0 + j2 + e;
        const float4* p = reinterpret_cast<const float4*>(A + ((size_t)n * HH + j) * 16);
        float4 a0 = p[0], a1 = p[1], a2 = p[2], a3 = p[3];
        float av[16] = {a0.x,a0.y,a0.z,a0.w, a1.x,a1.y,a1.z,a1.w,
                        a2.x,a2.y,a2.z,a2.w, a3.x,a3.y,a3.z,a3.w};
        float s = 0.f;
#pragma unroll
        for (int l = 0; l < 16; ++l) s += av[l];
        float m = s * 0.0625f;
        c[(size_t)n * HH + j] = m;
        hcat[(size_t)n * KTOT + j] = f2bf(m);        // h slot 0
#pragma unroll
        for (int l = 0; l < 16; ++l) lg[l] += m * av[l];
    }
#pragma unroll
    for (int l = 0; l < 16; ++l) {
        lg[l] += __shfl_xor(lg[l], 1);
        lg[l] += __shfl_xor(lg[l], 2);
        lg[l] += __shfl_xor(lg[l], 4);
    }
    int l0 = (tid & 7) * 2;
    atomicAdd(&lg0[(size_t)n * 16 + l0],     lg[l0]);
    atomicAdd(&lg0[(size_t)n * 16 + l0 + 1], lg[l0 + 1]);
}

// ---------------------------------------------------------------------------
// attn phase: softmax(logits/32) -> attn slice (bf16 into hcat[..,2048+j]);
// also zeroes the (t+2)%3 logits buffer
// ---------------------------------------------------------------------------
__global__ __launch_bounds__(512) void attn_phase(const float* __restrict__ lgcur,
                                                  float* __restrict__ lgz,
                                                  const float* __restrict__ A,
                                                  unsigned short* __restrict__ hcat) {
    int m0, j0; bmap(blockIdx.x, m0, j0);
    int tid = threadIdx.x;
    int r = tid >> 3, j2 = (tid & 7) * 2;
    int n = m0 + r;
    const float4* lp = reinterpret_cast<const float4*>(lgcur + (size_t)n * 16);
    float4 s0 = lp[0], s1 = lp[1], s2 = lp[2], s3 = lp[3];
    float s[16] = {s0.x,s0.y,s0.z,s0.w, s1.x,s1.y,s1.z,s1.w,
                   s2.x,s2.y,s2.z,s2.w, s3.x,s3.y,s3.z,s3.w};
    float mx = -1e30f;
#pragma unroll
    for (int l = 0; l < 16; ++l) { s[l] *= 0.03125f; mx = fmaxf(mx, s[l]); }
    float wsum = 0.f;
    float w[16];
#pragma unroll
    for (int l = 0; l < 16; ++l) { w[l] = __expf(s[l] - mx); wsum += w[l]; }
    float inv = 1.f / wsum;
#pragma unroll
    for (int e = 0; e < 2; ++e) {
        int j = j0 + j2 + e;
        const float4* p = reinterpret_cast<const float4*>(A + ((size_t)n * HH + j) * 16);
        float4 a0 = p[0], a1 = p[1], a2 = p[2], a3 = p[3];
        float av[16] = {a0.x,a0.y,a0.z,a0.w, a1.x,a1.y,a1.z,a1.w,
                        a2.x,a2.y,a2.z,a2.w, a3.x,a3.y,a3.z,a3.w};
        float acc = 0.f;
#pragma unroll
        for (int l = 0; l < 16; ++l) acc += av[l] * w[l];
        hcat[(size_t)n * KTOT + 2048 + j] = f2bf(acc * inv);
    }
    if ((blockIdx.x & 63) == 0) {     // j-tile 0 blocks zero the (t+2)%3 buffer
        int l0 = (tid & 7) * 2;
        lgz[(size_t)n * 16 + l0]     = 0.f;
        lgz[(size_t)n * 16 + l0 + 1] = 0.f;
    }
}

// ---------------------------------------------------------------------------
// K-chunk runners: barrier-free, fragments straight from global (L2-resident).
// Frag layout (verified): row/col = lane&15, 8 k-elems at (lane>>4)*8.
// ---------------------------------------------------------------------------
template<int N>
__device__ __forceinline__ void run_h(const unsigned short* const* ap,
                                      const unsigned short* const* bp,
                                      f32x4 (&acc)[4][4]) {
#pragma unroll
    for (int c2 = 0; c2 < N; ++c2) {
        short8 a[4], b[4];
#pragma unroll
        for (int i = 0; i < 4; ++i)
            a[i] = *reinterpret_cast<const short8*>(ap[i] + c2 * 32);
#pragma unroll
        for (int i = 0; i < 4; ++i)
            b[i] = *reinterpret_cast<const short8*>(bp[i] + c2 * 32);
#pragma unroll
        for (int mi = 0; mi < 4; ++mi)
#pragma unroll
            for (int ni = 0; ni < 4; ++ni)
                acc[mi][ni] = __builtin_amdgcn_mfma_f32_16x16x32_bf16(
                    a[mi], b[ni], acc[mi][ni], 0, 0, 0);
    }
}

template<int N>
__device__ __forceinline__ void run_x(const float* const* xp,
                                      const unsigned short* const* bp,
                                      f32x4 (&acc)[4][4]) {
#pragma unroll
    for (int c2 = 0; c2 < N; ++c2) {
        short8 a[4], b[4];
#pragma unroll
        for (int i = 0; i < 4; ++i) {
            float4 v0 = *reinterpret_cast<const float4*>(xp[i] + c2 * 32);
            float4 v1 = *reinterpret_cast<const float4*>(xp[i] + c2 * 32 + 4);
            a[i] = pack8(v0, v1);
        }
#pragma unroll
        for (int i = 0; i < 4; ++i)
            b[i] = *reinterpret_cast<const short8*>(bp[i] + c2 * 32);
#pragma unroll
        for (int mi = 0; mi < 4; ++mi)
#pragma unroll
            for (int ni = 0; ni < 4; ++ni)
                acc[mi][ni] = __builtin_amdgcn_mfma_f32_16x16x32_bf16(
                    a[mi], b[ni], acc[mi][ni], 0, 0, 0);
    }
}

// ---------------------------------------------------------------------------
// fused GEMM + LSTM update + logit partials.
// block: 64 rows x 64 c-cols (4 gates x 16 j). 8 waves, each: full 64x64 tile,
// K-slice of 384. No LDS/barriers in K-loop; 8-way partial reduce in LDS at end.
// ---------------------------------------------------------------------------
__global__ __launch_bounds__(512, 2) void gemm_fused(const float* __restrict__ x,
                                                     unsigned short* __restrict__ hcat,
                                                     const unsigned short* __restrict__ Wt,
                                                     const float* __restrict__ A,
                                                     const float* __restrict__ b,
                                                     float* __restrict__ c,
                                                     float* __restrict__ out,
                                                     float* __restrict__ lgnext, int t) {
    __shared__ float red[4][64][68];
    int m0, j0; bmap(blockIdx.x, m0, j0);
    int tid = threadIdx.x;
    int w = tid >> 6, lane = tid & 63;
    int hsel = t & 1;
    int ks = w * 384;
    int cw = lane & 15;
    int klane = (lane >> 4) << 3;

    f32x4 acc[4][4];
#pragma unroll
    for (int mi = 0; mi < 4; ++mi)
#pragma unroll
        for (int ni = 0; ni < 4; ++ni)
#pragma unroll
            for (int e = 0; e < 4; ++e) acc[mi][ni][e] = 0.f;

    const unsigned short* bp[4];
#pragma unroll
    for (int ni = 0; ni < 4; ++ni)
        bp[ni] = Wt + (size_t)(ni * 1024 + j0 + cw) * KTOT + ks + klane;

    if (w < 2) {                       // k slice fully in x [0,768)
        const float* xp[4];
#pragma unroll
        for (int mi = 0; mi < 4; ++mi)
            xp[mi] = x + ((size_t)(m0 + mi * 16 + cw) * TT + t) * DD + ks + klane;
        run_x<12>(xp, bp, acc);
    } else if (w == 2) {               // x [768,1024) then h [1024,1152)
        const float* xp[4];
#pragma unroll
        for (int mi = 0; mi < 4; ++mi)
            xp[mi] = x + ((size_t)(m0 + mi * 16 + cw) * TT + t) * DD + ks + klane;
        run_x<8>(xp, bp, acc);
        const unsigned short* hp[4];
        const unsigned short* bp2[4];
#pragma unroll
        for (int mi = 0; mi < 4; ++mi)
            hp[mi] = hcat + (size_t)(m0 + mi * 16 + cw) * KTOT + hsel * 1024 + klane;
#pragma unroll
        for (int ni = 0; ni < 4; ++ni) bp2[ni] = bp[ni] + 256;
        run_h<4>(hp, bp2, acc);
    } else if (w <= 4) {               // h region [1152,1920)
        const unsigned short* hp[4];
        int hoff = hsel * 1024 + (ks - 1024);
#pragma unroll
        for (int mi = 0; mi < 4; ++mi)
            hp[mi] = hcat + (size_t)(m0 + mi * 16 + cw) * KTOT + hoff + klane;
        run_h<12>(hp, bp, acc);
    } else if (w == 5) {               // h [1920,2048) then attn [2048,2304)
        const unsigned short* hp[4];
#pragma unroll
        for (int mi = 0; mi < 4; ++mi)
            hp[mi] = hcat + (size_t)(m0 + mi * 16 + cw) * KTOT + hsel * 1024 + 896 + klane;
        run_h<4>(hp, bp, acc);
        const unsigned short* hp2[4];
        const unsigned short* bp2[4];
#pragma unroll
        for (int mi = 0; mi < 4; ++mi)
            hp2[mi] = hcat + (size_t)(m0 + mi * 16 + cw) * KTOT + 2048 + klane;
#pragma unroll
        for (int ni = 0; ni < 4; ++ni) bp2[ni] = bp[ni] + 128;
        run_h<8>(hp2, bp2, acc);
    } else {                           // attn region [2304,3072)
        const unsigned short* hp[4];
#pragma unroll
        for (int mi = 0; mi < 4; ++mi)
            hp[mi] = hcat + (size_t)(m0 + mi * 16 + cw) * KTOT + ks + klane;
        run_h<12>(hp, bp, acc);
    }

    // ---- 8-way partial reduce in LDS (transposed: red[p][col][row]) ----
    int r0 = (lane >> 4) << 2;
    if (w < 4) {
#pragma unroll
        for (int mi = 0; mi < 4; ++mi)
#pragma unroll
            for (int ni = 0; ni < 4; ++ni)
                *reinterpret_cast<f32x4*>(&red[w][ni * 16 + cw][mi * 16 + r0]) = acc[mi][ni];
    }
    __syncthreads();
    if (w >= 4) {
#pragma unroll
        for (int mi = 0; mi < 4; ++mi)
#pragma unroll
            for (int ni = 0; ni < 4; ++ni) {
                f32x4 v = *reinterpret_cast<const f32x4*>(&red[w - 4][ni * 16 + cw][mi * 16 + r0]);
                v += acc[mi][ni];
                *reinterpret_cast<f32x4*>(&red[w - 4][ni * 16 + cw][mi * 16 + r0]) = v;
            }
    }
    __syncthreads();
#pragma unroll
    for (int s = 0; s < 2; ++s) {      // 1024 (col, row-quad) tasks, 2/thread
        int q = tid * 2 + s;
        int cc = q >> 4, r4 = (q & 15) << 2;
        f32x4 sum = *reinterpret_cast<const f32x4*>(&red[0][cc][r4]);
#pragma unroll
        for (int p = 1; p < 4; ++p)
            sum += *reinterpret_cast<const f32x4*>(&red[p][cc][r4]);
        *reinterpret_cast<f32x4*>(&red[0][cc][r4]) = sum;
    }
    __syncthreads();

    // ---- LSTM update + logit partials ----
    int r = tid >> 3, j2 = (tid & 7) * 2;
    int n = m0 + r;
    int j = j0 + j2;
    float2 cv = *reinterpret_cast<const float2*>(c + (size_t)n * HH + j);
    float hn[2], cn[2];
#pragma unroll
    for (int e = 0; e < 2; ++e) {
        float ig = sigm(red[0][0 * 16 + j2 + e][r] + b[0 * HH + j + e]);
        float fg = sigm(red[0][1 * 16 + j2 + e][r] + b[1 * HH + j + e]);
        float og = sigm(red[0][2 * 16 + j2 + e][r] + b[2 * HH + j + e]);
        float gg = tanhf_(red[0][3 * 16 + j2 + e][r] + b[3 * HH + j + e]);
        float cc = fg * (e ? cv.y : cv.x) + ig * gg;
        cn[e] = cc;
        hn[e] = og * tanhf_(cc);
    }
    *reinterpret_cast<float2*>(c + (size_t)n * HH + j) = make_float2(cn[0], cn[1]);
    hcat[(size_t)n * KTOT + (hsel ^ 1) * 1024 + j]     = f2bf(hn[0]);
    hcat[(size_t)n * KTOT + (hsel ^ 1) * 1024 + j + 1] = f2bf(hn[1]);
    *reinterpret_cast<float2*>(out + ((size_t)n * TT + t) * HH + j) = make_float2(hn[0], hn[1]);

    float lg[16];
#pragma unroll
    for (int l = 0; l < 16; ++l) lg[l] = 0.f;
#pragma unroll
    for (int e = 0; e < 2; ++e) {
        const float4* p = reinterpret_cast<const float4*>(A + ((size_t)n * HH + j + e) * 16);
        float4 a0 = p[0], a1 = p[1], a2 = p[2], a3 = p[3];
        float av[16] = {a0.x,a0.y,a0.z,a0.w, a1.x,a1.y,a1.z,a1.w,
                        a2.x,a2.y,a2.z,a2.w, a3.x,a3.y,a3.z,a3.w};
        float hv = hn[e];
#pragma unroll
        for (int l = 0; l < 16; ++l) lg[l] += hv * av[l];
    }
#pragma unroll
    for (int l = 0; l < 16; ++l) {
        lg[l] += __shfl_xor(lg[l], 1);
        lg[l] += __shfl_xor(lg[l], 2);
        lg[l] += __shfl_xor(lg[l], 4);
    }
    int l0 = (tid & 7) * 2;
    atomicAdd(&lgnext[(size_t)n * 16 + l0],     lg[l0]);
    atomicAdd(&lgnext[(size_t)n * 16 + l0 + 1], lg[l0 + 1]);
}

// ---------------------------------------------------------------------------
extern "C" void kernel_launch(void* const* d_in, const int* in_sizes, int n_in,
                              void* d_out, int out_size, void* d_ws, size_t ws_size,
                              hipStream_t stream) {
    const float* x     = (const float*)d_in[0];
    const float* A     = (const float*)d_in[1];
    const float* Wx    = (const float*)d_in[2];
    const float* Wh    = (const float*)d_in[3];
    const float* Wattn = (const float*)d_in[4];
    const float* b     = (const float*)d_in[5];
    float* out = (float*)d_out;

    char* ws = (char*)d_ws;
    unsigned short* Wt   = (unsigned short*)(ws);              // 25,165,824 B
    unsigned short* hcat = (unsigned short*)(ws + 25165824);   //  1,572,864 B  [h0|h1|attn]
    float* c             = (float*)(ws + 26738688);            //  1,048,576 B
    float* lg            = (float*)(ws + 27787264);            //     49,152 B  (3 bufs)

    wt_prep<<<dim3(48, 64), 256, 0, stream>>>(Wx, Wh, Wattn, Wt);
    zero_buf<<<48, 256, 0, stream>>>(lg, 3 * NB * 16);
    init_kernel<<<256, 512, 0, stream>>>(A, c, hcat, lg);
    for (int t = 0; t < TT; ++t) {
        attn_phase<<<256, 512, 0, stream>>>(lg + (t % 3) * NB * 16,
                                            lg + ((t + 2) % 3) * NB * 16, A, hcat);
        gemm_fused<<<256, 512, 0, stream>>>(x, hcat, Wt, A, b, c, out,
                                            lg + ((t + 1) % 3) * NB * 16, t);
    }
}

// Round 4
// 4220.037 us; speedup vs baseline: 1.3794x; 1.3794x over previous
//
#include <hip/hip_runtime.h>
#include <hip/hip_bf16.h>

#define NB 256
#define TT 128
#define DD 1024
#define HH 1024
#define FH 4096
#define KTOT 3072

typedef __attribute__((ext_vector_type(4))) float f32x4;
typedef __attribute__((ext_vector_type(8))) short short8;

__device__ __forceinline__ unsigned short f2bf(float f) {
    union { float f; unsigned u; } v; v.f = f;
    unsigned u = v.u;
    u += 0x7FFFu + ((u >> 16) & 1u);   // RNE
    return (unsigned short)(u >> 16);
}
__device__ __forceinline__ float bf2f(unsigned short u) {
    union { unsigned u; float f; } v; v.u = ((unsigned)u) << 16; return v.f;
}
__device__ __forceinline__ float sigm(float v) { return 1.f / (1.f + __expf(-v)); }
__device__ __forceinline__ float tanhf_(float v) { return 1.f - 2.f / (__expf(2.f * v) + 1.f); }

__device__ __forceinline__ void bmap(int bid, int& m0, int& j0) {
    int xx = bid & 7, yy = (bid >> 3) & 7, mt = bid >> 6;
    m0 = mt * 64;
    j0 = (xx * 8 + yy) * 16;           // XCD-aligned j tiles
}

__device__ __forceinline__ short8 pack8(float4 v0, float4 v1) {
    short8 r;
    r[0] = (short)f2bf(v0.x); r[1] = (short)f2bf(v0.y);
    r[2] = (short)f2bf(v0.z); r[3] = (short)f2bf(v0.w);
    r[4] = (short)f2bf(v1.x); r[5] = (short)f2bf(v1.y);
    r[6] = (short)f2bf(v1.z); r[7] = (short)f2bf(v1.w);
    return r;
}

// ---------------------------------------------------------------------------
// Wt[c][k] bf16: c = gate*1024+j (4096), k = concat(x:0..1023, h:1024..2047,
// attn-weight rows 2048..3071 used only by the G precompute)
// ---------------------------------------------------------------------------
__global__ __launch_bounds__(256) void wt_prep(const float* __restrict__ Wx,
                                               const float* __restrict__ Wh,
                                               const float* __restrict__ Wattn,
                                               unsigned short* __restrict__ Wt) {
    __shared__ unsigned short tile[64][65];
    int k0 = blockIdx.x * 64;   // 48
    int c0 = blockIdx.y * 64;   // 64
    const float* src; int kl0;
    if (k0 < 1024)      { src = Wx;    kl0 = k0; }
    else if (k0 < 2048) { src = Wh;    kl0 = k0 - 1024; }
    else                { src = Wattn; kl0 = k0 - 2048; }
    int tid = threadIdx.x;
    int r = tid >> 2;
    int ch = (tid & 3) << 4;
    const float* p = src + (size_t)(kl0 + r) * FH + c0 + ch;
#pragma unroll
    for (int i = 0; i < 16; i += 4) {
        float4 v = *reinterpret_cast<const float4*>(p + i);
        tile[r][ch + i + 0] = f2bf(v.x);
        tile[r][ch + i + 1] = f2bf(v.y);
        tile[r][ch + i + 2] = f2bf(v.z);
        tile[r][ch + i + 3] = f2bf(v.w);
    }
    __syncthreads();
    alignas(16) unsigned short vals[16];
#pragma unroll
    for (int i = 0; i < 16; ++i) vals[i] = tile[ch + i][r];
    unsigned short* q = Wt + (size_t)(c0 + r) * KTOT + k0 + ch;
    *reinterpret_cast<uint4*>(q)     = *reinterpret_cast<uint4*>(&vals[0]);
    *reinterpret_cast<uint4*>(q + 8) = *reinterpret_cast<uint4*>(&vals[8]);
}

__global__ __launch_bounds__(256) void zero_buf(float* __restrict__ p, int n) {
    int i = blockIdx.x * 256 + threadIdx.x;
    if (i < n) p[i] = 0.f;
}

// x (fp32) -> xbf (bf16), same [n][t][d] layout
__global__ __launch_bounds__(256) void xconv(const float* __restrict__ x,
                                             unsigned short* __restrict__ xbf) {
    size_t i = ((size_t)blockIdx.x * 256 + threadIdx.x) * 8;
    float4 v0 = *reinterpret_cast<const float4*>(x + i);
    float4 v1 = *reinterpret_cast<const float4*>(x + i + 4);
    short8 p = pack8(v0, v1);
    *reinterpret_cast<short8*>(xbf + i) = p;
}

// AfT[n][l][h] = bf16(A[n][h][l])
__global__ __launch_bounds__(256) void afT_prep(const float* __restrict__ A,
                                                unsigned short* __restrict__ AfT) {
    int n = blockIdx.x;
#pragma unroll
    for (int pass = 0; pass < 4; ++pass) {
        int hh = pass * 256 + threadIdx.x;
        const float4* p = reinterpret_cast<const float4*>(A + ((size_t)n * HH + hh) * 16);
        float4 a0 = p[0], a1 = p[1], a2 = p[2], a3 = p[3];
        float av[16] = {a0.x,a0.y,a0.z,a0.w, a1.x,a1.y,a1.z,a1.w,
                        a2.x,a2.y,a2.z,a2.w, a3.x,a3.y,a3.z,a3.w};
#pragma unroll
        for (int l = 0; l < 16; ++l)
            AfT[((size_t)n * 16 + l) * HH + hh] = f2bf(av[l]);
    }
}

// ---------------------------------------------------------------------------
// G[n][c][l] = sum_h Af[n][h][l] * Wattn[h][c]   (bf16, l contiguous)
// grid (32 col-tiles of 128, 256 n); 4 waves, each 16(l) x 32(c), K=1024
// ---------------------------------------------------------------------------
__global__ __launch_bounds__(256) void g_gemm(const unsigned short* __restrict__ AfT,
                                              const unsigned short* __restrict__ Wt,
                                              unsigned short* __restrict__ G) {
    int n = blockIdx.y;
    int ct = blockIdx.x;
    int tid = threadIdx.x;
    int wv = tid >> 6, lane = tid & 63;
    int cw = lane & 15, k8 = (lane >> 4) << 3;
    const unsigned short* ap  = AfT + ((size_t)n * 16 + cw) * HH + k8;
    const unsigned short* bp0 = Wt + (size_t)(ct * 128 + wv * 32 + cw) * KTOT + 2048 + k8;
    const unsigned short* bp1 = Wt + (size_t)(ct * 128 + wv * 32 + 16 + cw) * KTOT + 2048 + k8;
    f32x4 acc0, acc1;
#pragma unroll
    for (int e = 0; e < 4; ++e) { acc0[e] = 0.f; acc1[e] = 0.f; }
#pragma unroll
    for (int ch = 0; ch < 32; ++ch) {
        short8 a  = *reinterpret_cast<const short8*>(ap  + ch * 32);
        short8 b0 = *reinterpret_cast<const short8*>(bp0 + ch * 32);
        short8 b1 = *reinterpret_cast<const short8*>(bp1 + ch * 32);
        acc0 = __builtin_amdgcn_mfma_f32_16x16x32_bf16(a, b0, acc0, 0, 0, 0);
        acc1 = __builtin_amdgcn_mfma_f32_16x16x32_bf16(a, b1, acc1, 0, 0, 0);
    }
    int r0 = (lane >> 4) << 2;
    int c0 = ct * 128 + wv * 32 + cw;
#pragma unroll
    for (int e = 0; e < 4; ++e) {
        int l = r0 + e;
        G[((size_t)n * FH + c0) * 16 + l]      = f2bf(acc0[e]);
        G[((size_t)n * FH + c0 + 16) * 16 + l] = f2bf(acc1[e]);
    }
}

// ---------------------------------------------------------------------------
// init: h0 = c0 = mean(Af[n,h,:]); h0 bf16 -> hbuf slot 0; logits(h0) -> lg0
// ---------------------------------------------------------------------------
__global__ __launch_bounds__(512) void init_kernel(const float* __restrict__ A,
                                                   float* __restrict__ c,
                                                   unsigned short* __restrict__ h0,
                                                   float* __restrict__ lg0) {
    int m0, j0; bmap(blockIdx.x, m0, j0);
    int tid = threadIdx.x;
    int r = tid >> 3, j2 = (tid & 7) * 2;
    int n = m0 + r;
    float lg[16];
#pragma unroll
    for (int l = 0; l < 16; ++l) lg[l] = 0.f;
#pragma unroll
    for (int e = 0; e < 2; ++e) {
        int j = j0 + j2 + e;
        const float4* p = reinterpret_cast<const float4*>(A + ((size_t)n * HH + j) * 16);
        float4 a0 = p[0], a1 = p[1], a2 = p[2], a3 = p[3];
        float av[16] = {a0.x,a0.y,a0.z,a0.w, a1.x,a1.y,a1.z,a1.w,
                        a2.x,a2.y,a2.z,a2.w, a3.x,a3.y,a3.z,a3.w};
        float s = 0.f;
#pragma unroll
        for (int l = 0; l < 16; ++l) s += av[l];
        float m = s * 0.0625f;
        c[(size_t)n * HH + j] = m;
        h0[(size_t)n * HH + j] = f2bf(m);
#pragma unroll
        for (int l = 0; l < 16; ++l) lg[l] += m * av[l];
    }
#pragma unroll
    for (int l = 0; l < 16; ++l) {
        lg[l] += __shfl_xor(lg[l], 1);
        lg[l] += __shfl_xor(lg[l], 2);
        lg[l] += __shfl_xor(lg[l], 4);
    }
    int l0 = (tid & 7) * 2;
    atomicAdd(&lg0[(size_t)n * 16 + l0],     lg[l0]);
    atomicAdd(&lg0[(size_t)n * 16 + l0 + 1], lg[l0 + 1]);
}

// ---------------------------------------------------------------------------
// Per-step fused kernel: pre = [x_t|h] @ Wt(K=2048) + w·G + b; LSTM update;
// h/out/c writes; next-step logit partials. One dispatch per step.
// Block: 64 rows x 64 cols (4 gates x 16 j). 8 waves = 2n x 4k:
//   wave tile 64 rows x 32 cols, K-quarter 512 (quarters 0,1 = x; 2,3 = h-LDS)
// ---------------------------------------------------------------------------
template<bool XBF>
__global__ __launch_bounds__(512)
void gemm_step(const float* __restrict__ x, const unsigned short* __restrict__ xbf,
               const unsigned short* __restrict__ hprev, unsigned short* __restrict__ hnext,
               const unsigned short* __restrict__ Wt, const unsigned short* __restrict__ G,
               const float* __restrict__ A, const float* __restrict__ bb,
               const float* __restrict__ lgcur, float* __restrict__ lgnext,
               float* __restrict__ lgz, float* __restrict__ c,
               float* __restrict__ out, int t) {
    __shared__ __attribute__((aligned(16))) char smem[131072];
    unsigned short* hsm = reinterpret_cast<unsigned short*>(smem);  // [64][1024] swizzled
    float* gsm = reinterpret_cast<float*>(smem);                    // [4][64][68] (after K-loop)

    int m0, j0; bmap(blockIdx.x, m0, j0);
    int tid = threadIdx.x;
    int w = tid >> 6, lane = tid & 63;
    int wn = w & 1, wk = w >> 1;

    // ---- stage h tile into LDS (16B chunks, XOR swizzle chunk^(row&7)) ----
    {
        int r = tid >> 3;
        const unsigned short* hp = hprev + (size_t)(m0 + r) * HH;
#pragma unroll
        for (int i = 0; i < 16; ++i) {
            int chunk = (tid & 7) + i * 8;        // 0..127
            int sw = chunk ^ (r & 7);
            *reinterpret_cast<uint4*>(&hsm[r * 1024 + sw * 8]) =
                *reinterpret_cast<const uint4*>(hp + chunk * 8);
        }
    }
    __syncthreads();

    int cw = lane & 15;
    int k8 = (lane >> 4) << 3;

    f32x4 acc[4][2];
#pragma unroll
    for (int mf = 0; mf < 4; ++mf)
#pragma unroll
        for (int fn = 0; fn < 2; ++fn)
#pragma unroll
            for (int e = 0; e < 4; ++e) acc[mf][fn][e] = 0.f;

    const unsigned short* bp[2];
#pragma unroll
    for (int fn = 0; fn < 2; ++fn) {
        int col = wn * 32 + fn * 16 + cw;
        int brow = (col >> 4) * 1024 + j0 + (col & 15);
        int kbase = (wk < 2) ? (wk * 512) : (1024 + (wk - 2) * 512);
        bp[fn] = Wt + (size_t)brow * KTOT + kbase + k8;
    }

    if (wk < 2) {                      // x region, direct from global
        if (XBF) {
            const unsigned short* ap[4];
#pragma unroll
            for (int mf = 0; mf < 4; ++mf)
                ap[mf] = xbf + ((size_t)(m0 + mf * 16 + cw) * TT + t) * DD + wk * 512 + k8;
#pragma unroll
            for (int ch = 0; ch < 16; ++ch) {
                short8 b0 = *reinterpret_cast<const short8*>(bp[0] + ch * 32);
                short8 b1 = *reinterpret_cast<const short8*>(bp[1] + ch * 32);
#pragma unroll
                for (int mf = 0; mf < 4; ++mf) {
                    short8 a = *reinterpret_cast<const short8*>(ap[mf] + ch * 32);
                    acc[mf][0] = __builtin_amdgcn_mfma_f32_16x16x32_bf16(a, b0, acc[mf][0], 0, 0, 0);
                    acc[mf][1] = __builtin_amdgcn_mfma_f32_16x16x32_bf16(a, b1, acc[mf][1], 0, 0, 0);
                }
            }
        } else {
            const float* ap[4];
#pragma unroll
            for (int mf = 0; mf < 4; ++mf)
                ap[mf] = x + ((size_t)(m0 + mf * 16 + cw) * TT + t) * DD + wk * 512 + k8;
#pragma unroll
            for (int ch = 0; ch < 16; ++ch) {
                short8 b0 = *reinterpret_cast<const short8*>(bp[0] + ch * 32);
                short8 b1 = *reinterpret_cast<const short8*>(bp[1] + ch * 32);
#pragma unroll
                for (int mf = 0; mf < 4; ++mf) {
                    float4 v0 = *reinterpret_cast<const float4*>(ap[mf] + ch * 32);
                    float4 v1 = *reinterpret_cast<const float4*>(ap[mf] + ch * 32 + 4);
                    short8 a = pack8(v0, v1);
                    acc[mf][0] = __builtin_amdgcn_mfma_f32_16x16x32_bf16(a, b0, acc[mf][0], 0, 0, 0);
                    acc[mf][1] = __builtin_amdgcn_mfma_f32_16x16x32_bf16(a, b1, acc[mf][1], 0, 0, 0);
                }
            }
        }
    } else {                           // h region, from swizzled LDS
        int kq = (wk - 2) * 512;
        int chunkBase = (kq + k8) >> 3;
#pragma unroll
        for (int ch = 0; ch < 16; ++ch) {
            short8 b0 = *reinterpret_cast<const short8*>(bp[0] + ch * 32);
            short8 b1 = *reinterpret_cast<const short8*>(bp[1] + ch * 32);
            int chunkI = chunkBase + ch * 4;
#pragma unroll
            for (int mf = 0; mf < 4; ++mf) {
                int row = mf * 16 + cw;
                int sw = chunkI ^ (row & 7);
                short8 a = *reinterpret_cast<const short8*>(&hsm[row * 1024 + sw * 8]);
                acc[mf][0] = __builtin_amdgcn_mfma_f32_16x16x32_bf16(a, b0, acc[mf][0], 0, 0, 0);
                acc[mf][1] = __builtin_amdgcn_mfma_f32_16x16x32_bf16(a, b1, acc[mf][1], 0, 0, 0);
            }
        }
    }

    __syncthreads();                   // hsm reads done; reuse LDS as gsm
    int r0 = (lane >> 4) << 2;
#pragma unroll
    for (int mf = 0; mf < 4; ++mf)
#pragma unroll
        for (int fn = 0; fn < 2; ++fn)
#pragma unroll
            for (int e = 0; e < 4; ++e)
                gsm[((size_t)wk * 64 + mf * 16 + r0 + e) * 68 + wn * 32 + fn * 16 + cw] =
                    acc[mf][fn][e];
    __syncthreads();

    // ---- epilogue: softmax(w) + w*G + bias + LSTM + logits(t+1) ----
    int r = tid >> 3, j2 = (tid & 7) * 2;
    int n = m0 + r;

    float sm[16];
    {
        const float4* lp = reinterpret_cast<const float4*>(lgcur + (size_t)n * 16);
        float4 s0 = lp[0], s1 = lp[1], s2 = lp[2], s3 = lp[3];
        float s[16] = {s0.x,s0.y,s0.z,s0.w, s1.x,s1.y,s1.z,s1.w,
                       s2.x,s2.y,s2.z,s2.w, s3.x,s3.y,s3.z,s3.w};
        float mx = -1e30f;
#pragma unroll
        for (int l = 0; l < 16; ++l) { s[l] *= 0.03125f; mx = fmaxf(mx, s[l]); }
        float sum = 0.f;
#pragma unroll
        for (int l = 0; l < 16; ++l) { sm[l] = __expf(s[l] - mx); sum += sm[l]; }
        float inv = 1.f / sum;
#pragma unroll
        for (int l = 0; l < 16; ++l) sm[l] *= inv;
    }

    float pre[4][2];
#pragma unroll
    for (int g = 0; g < 4; ++g)
#pragma unroll
        for (int e = 0; e < 2; ++e) {
            int colL = g * 16 + j2 + e;
            float p = gsm[((size_t)0 * 64 + r) * 68 + colL]
                    + gsm[((size_t)1 * 64 + r) * 68 + colL]
                    + gsm[((size_t)2 * 64 + r) * 68 + colL]
                    + gsm[((size_t)3 * 64 + r) * 68 + colL];
            p += bb[g * HH + j0 + j2 + e];
            const unsigned short* gp = G + ((size_t)n * FH + g * HH + j0 + j2 + e) * 16;
            uint4 g0 = *reinterpret_cast<const uint4*>(gp);
            uint4 g1 = *reinterpret_cast<const uint4*>(gp + 8);
            const unsigned* gu = reinterpret_cast<const unsigned*>(&g0);
            float d = 0.f;
#pragma unroll
            for (int q = 0; q < 4; ++q) {
                d += sm[q * 2]     * bf2f((unsigned short)(gu[q] & 0xFFFF));
                d += sm[q * 2 + 1] * bf2f((unsigned short)(gu[q] >> 16));
            }
            const unsigned* gv = reinterpret_cast<const unsigned*>(&g1);
#pragma unroll
            for (int q = 0; q < 4; ++q) {
                d += sm[8 + q * 2]     * bf2f((unsigned short)(gv[q] & 0xFFFF));
                d += sm[8 + q * 2 + 1] * bf2f((unsigned short)(gv[q] >> 16));
            }
            pre[g][e] = p + d;
        }

    int j = j0 + j2;
    float2 cv = *reinterpret_cast<const float2*>(c + (size_t)n * HH + j);
    float hn[2], cn[2];
#pragma unroll
    for (int e = 0; e < 2; ++e) {
        float ig = sigm(pre[0][e]);
        float fg = sigm(pre[1][e]);
        float og = sigm(pre[2][e]);
        float gg = tanhf_(pre[3][e]);
        float cc = fg * (e ? cv.y : cv.x) + ig * gg;
        cn[e] = cc;
        hn[e] = og * tanhf_(cc);
    }
    *reinterpret_cast<float2*>(c + (size_t)n * HH + j) = make_float2(cn[0], cn[1]);
    unsigned hpack = (unsigned)f2bf(hn[0]) | ((unsigned)f2bf(hn[1]) << 16);
    *reinterpret_cast<unsigned*>(hnext + (size_t)n * HH + j) = hpack;
    *reinterpret_cast<float2*>(out + ((size_t)n * TT + t) * HH + j) = make_float2(hn[0], hn[1]);

    if ((blockIdx.x & 63) == 0) {      // one block per m-tile zeroes lg(t+2)
        int l0 = (tid & 7) * 2;
        lgz[(size_t)n * 16 + l0]     = 0.f;
        lgz[(size_t)n * 16 + l0 + 1] = 0.f;
    }

    float lg[16];
#pragma unroll
    for (int l = 0; l < 16; ++l) lg[l] = 0.f;
#pragma unroll
    for (int e = 0; e < 2; ++e) {
        const float4* p = reinterpret_cast<const float4*>(A + ((size_t)n * HH + j + e) * 16);
        float4 a0 = p[0], a1 = p[1], a2 = p[2], a3 = p[3];
        float av[16] = {a0.x,a0.y,a0.z,a0.w, a1.x,a1.y,a1.z,a1.w,
                        a2.x,a2.y,a2.z,a2.w, a3.x,a3.y,a3.z,a3.w};
        float hv = hn[e];
#pragma unroll
        for (int l = 0; l < 16; ++l) lg[l] += hv * av[l];
    }
#pragma unroll
    for (int l = 0; l < 16; ++l) {
        lg[l] += __shfl_xor(lg[l], 1);
        lg[l] += __shfl_xor(lg[l], 2);
        lg[l] += __shfl_xor(lg[l], 4);
    }
    int l0 = (tid & 7) * 2;
    atomicAdd(&lgnext[(size_t)n * 16 + l0],     lg[l0]);
    atomicAdd(&lgnext[(size_t)n * 16 + l0 + 1], lg[l0 + 1]);
}

// ---------------------------------------------------------------------------
extern "C" void kernel_launch(void* const* d_in, const int* in_sizes, int n_in,
                              void* d_out, int out_size, void* d_ws, size_t ws_size,
                              hipStream_t stream) {
    const float* x     = (const float*)d_in[0];
    const float* A     = (const float*)d_in[1];
    const float* Wx    = (const float*)d_in[2];
    const float* Wh    = (const float*)d_in[3];
    const float* Wattn = (const float*)d_in[4];
    const float* b     = (const float*)d_in[5];
    float* out = (float*)d_out;

    char* ws = (char*)d_ws;
    unsigned short* Wt   = (unsigned short*)(ws);              // 25,165,824
    unsigned short* G    = (unsigned short*)(ws + 25165824);   // 33,554,432
    unsigned short* AfT  = (unsigned short*)(ws + 58720256);   //  8,388,608
    unsigned short* hbuf = (unsigned short*)(ws + 67108864);   //  1,048,576 (2 slots)
    float* c             = (float*)(ws + 68157440);            //  1,048,576
    float* lg            = (float*)(ws + 69206016);            //     49,152 (3 bufs)
    unsigned short* xbf  = (unsigned short*)(ws + 69255168);   // 67,108,864 (optional)
    bool use_xbf = ws_size >= (size_t)69255168 + 67108864;

    wt_prep<<<dim3(48, 64), 256, 0, stream>>>(Wx, Wh, Wattn, Wt);
    zero_buf<<<48, 256, 0, stream>>>(lg, 3 * NB * 16);
    afT_prep<<<NB, 256, 0, stream>>>(A, AfT);
    g_gemm<<<dim3(32, NB), 256, 0, stream>>>(AfT, Wt, G);
    init_kernel<<<256, 512, 0, stream>>>(A, c, hbuf, lg);
    if (use_xbf) xconv<<<16384, 256, 0, stream>>>(x, xbf);

    for (int t = 0; t < TT; ++t) {
        const unsigned short* hp = hbuf + (size_t)(t & 1) * NB * HH;
        unsigned short* hx       = hbuf + (size_t)((t & 1) ^ 1) * NB * HH;
        float* lgc = lg + (size_t)(t % 3) * NB * 16;
        float* lgn = lg + (size_t)((t + 1) % 3) * NB * 16;
        float* lgzz = lg + (size_t)((t + 2) % 3) * NB * 16;
        if (use_xbf)
            gemm_step<true><<<256, 512, 0, stream>>>(x, xbf, hp, hx, Wt, G, A, b,
                                                     lgc, lgn, lgzz, c, out, t);
        else
            gemm_step<false><<<256, 512, 0, stream>>>(x, xbf, hp, hx, Wt, G, A, b,
                                                      lgc, lgn, lgzz, c, out, t);
    }
}